// Round 12
// baseline (1091.882 us; speedup 1.0000x reference)
//
#include <hip/hip_runtime.h>

#define N_ITEMS 20000
#define N_USERS 2048
#define NNZ     4000000
#define LDP     2112   // padded XT leading dim (66 cache lines: breaks L2/L3 set aliasing)
#define CAP     320    // per-row bucket capacity; rows ~Poisson(200), P(overflow) ~ 1e-13

typedef float    f32x4 __attribute__((ext_vector_type(4)));
typedef unsigned u32x4 __attribute__((ext_vector_type(4)));

// ---------------- ws layout (bytes) ----------------
#define OFF_XT     ((size_t)0)                    // bf16 [20000][2112] = 84,480,000
#define OFF_CSRPK  ((size_t)84480000)             // u32 [20000*320] (col<<16 | bf16val) = 25,600,000
#define OFF_CNT    (OFF_CSRPK + 25600000)         // int [20000]

static __device__ __forceinline__ unsigned short f2bf(float f) {
  unsigned u = __float_as_uint(f);
  unsigned r = (u + 0x7fffu + ((u >> 16) & 1u)) >> 16;
  return (unsigned short)r;
}

#define NT_BLOCKS (313 * 32)                 // transpose tiles
#define NS_BLOCKS ((NNZ / 4 + 255) / 256)    // scatter blocks (4 nnz/thread)

// Fused: transpose X -> XT (bf16, padded) + COO -> fixed-capacity row buckets.
// csr_pk entry = (col << 16) | bf16(val)   (col < 32768 fits 16 bits)
__global__ __launch_bounds__(256) void prep_kernel(
    const float* __restrict__ X, const float* __restrict__ vals,
    const int* __restrict__ rows, const int* __restrict__ cols,
    unsigned short* __restrict__ XT, int* __restrict__ cnt,
    unsigned* __restrict__ csr_pk) {
  int b = blockIdx.x;
  if (b < NT_BLOCKS) {
    __shared__ float tile[64][65];
    int k0 = (b % 313) * 64;
    int u0 = (b / 313) * 64;
    int lane = threadIdx.x & 63;
    int dq = threadIdx.x >> 6;
    #pragma unroll
    for (int m = 0; m < 16; ++m) {
      int u = u0 + dq + 4 * m;
      int k = k0 + lane;
      float v = 0.f;
      if (k < N_ITEMS) v = X[(size_t)u * N_ITEMS + k];
      tile[lane][dq + 4 * m] = v;
    }
    __syncthreads();
    #pragma unroll
    for (int m = 0; m < 16; ++m) {
      int k = k0 + dq + 4 * m;
      if (k < N_ITEMS)
        XT[(size_t)k * LDP + u0 + lane] = f2bf(tile[dq + 4 * m][lane]);
    }
  } else {
    int i = ((b - NT_BLOCKS) * 256 + threadIdx.x) * 4;
    if (i < NNZ) {  // NNZ % 4 == 0: quads always complete
      int4   r4 = *reinterpret_cast<const int4*>(rows + i);
      int4   c4 = *reinterpret_cast<const int4*>(cols + i);
      float4 v4 = *reinterpret_cast<const float4*>(vals + i);
      #pragma unroll
      for (int k = 0; k < 4; ++k) {
        int   r = (k == 0) ? r4.x : (k == 1) ? r4.y : (k == 2) ? r4.z : r4.w;
        int   c = (k == 0) ? c4.x : (k == 1) ? c4.y : (k == 2) ? c4.z : c4.w;
        float v = (k == 0) ? v4.x : (k == 1) ? v4.y : (k == 2) ? v4.z : v4.w;
        int pos = atomicAdd(&cnt[r], 1);
        if (pos >= CAP) pos = CAP - 1;  // astronomically unlikely; stay in-bounds
        csr_pk[r * CAP + pos] = ((unsigned)c << 16) | (unsigned)f2bf(v);
      }
    }
  }
}

// Out[u,r] = sum_j val(j) * XT[col(j)][u]
// WG: 256 thr = 4 waves; 16 rows x 128 users (2 users/lane, dword gathers).
// grid = 1250 rb * 16 uchunks; xcd = wg&7 owns uchunks {2x,2x+1}.
// Gather addr = SGPR base (xt+u0, wave-uniform) + 32-bit voffset
// ((E>>16)*4224 + 4*lane) -> no 64-bit VGPR adds. val = bits(E<<16) exact.
// 3-deep software pipeline: while FMA8(b) runs, gathers b+1,b+2 in flight.
// Buckets zero-padded to x8 (memset) -> no tail loop.
__global__ __launch_bounds__(256) void spmm_kernel(
    const int* __restrict__ cnt, const unsigned* __restrict__ csr_pk,
    const unsigned short* __restrict__ xt, float* __restrict__ out) {
  __shared__ float tile[16][132];
  int wg = blockIdx.x;
  int xcd = wg & 7;
  int slot = wg >> 3;            // [0, 2500)
  int combo = slot / 1250;       // 0..1
  int rb = slot - combo * 1250;  // [0, 1250)
  int uchunk = xcd * 2 + combo;
  int u0 = uchunk * 128;
  int r0 = rb * 16;
  int lane = threadIdx.x & 63;
  int wave = __builtin_amdgcn_readfirstlane((int)(threadIdx.x >> 6));
  const char* xtb = (const char*)(xt + u0);  // wave-uniform base (SGPR)
  unsigned lane4 = 4 * (unsigned)lane;

#define LOAD8(E, BASE)                                                   \
  { u32x4 q0 = *reinterpret_cast<const u32x4*>(csr_pk + (BASE));         \
    u32x4 q1 = *reinterpret_cast<const u32x4*>(csr_pk + (BASE) + 4);     \
    E[0] = q0.x; E[1] = q0.y; E[2] = q0.z; E[3] = q0.w;                  \
    E[4] = q1.x; E[5] = q1.y; E[6] = q1.z; E[7] = q1.w; }
#define GATHER8(G, E)                                                    \
  { _Pragma("unroll")                                                    \
    for (int k = 0; k < 8; ++k)                                          \
      G[k] = *reinterpret_cast<const unsigned*>(                         \
          xtb + ((E[k] >> 16) * (unsigned)(LDP * 2) + lane4)); }
#define FMA8(G, E)                                                       \
  { _Pragma("unroll")                                                    \
    for (int k = 0; k < 8; ++k) {                                        \
      float v  = __uint_as_float(E[k] << 16);     /* exact bf16 */       \
      float xl = __uint_as_float(G[k] << 16);                            \
      float xh = __uint_as_float(G[k]);           /* lo bits = noise */  \
      if (k & 1) { a2 = fmaf(v, xl, a2); a3 = fmaf(v, xh, a3); }         \
      else       { a0 = fmaf(v, xl, a0); a1 = fmaf(v, xh, a1); }         \
    } }

  #pragma unroll 1
  for (int rr = 0; rr < 4; ++rr) {
    int r = r0 + wave * 4 + rr;
    int jb = r * CAP;
    int cr = __builtin_amdgcn_readfirstlane(cnt[r]);
    if (cr > CAP) cr = CAP;
    int nb = (cr + 7) >> 3;  // zero-padded buckets: all batches full
    float a0 = 0.f, a1 = 0.f, a2 = 0.f, a3 = 0.f;
    if (nb >= 3) {
      unsigned e0[8], e1[8], e2[8], g0[8], g1[8], g2[8];
      LOAD8(e0, jb)
      GATHER8(g0, e0)
      LOAD8(e1, jb + 8)
      GATHER8(g1, e1)
      LOAD8(e2, jb + 16)
      int b = 0;
      // invariant at top: g0=g(b), g1=g(b+1) issued; e2=entries(b+2) loaded
      for (; b + 5 < nb; b += 3) {
        GATHER8(g2, e2)              // issue b+2
        FMA8(g0, e0)                 // consume b
        LOAD8(e0, jb + (b + 3) * 8)
        GATHER8(g0, e0)              // issue b+3
        FMA8(g1, e1)                 // consume b+1
        LOAD8(e1, jb + (b + 4) * 8)
        GATHER8(g1, e1)              // issue b+4
        FMA8(g2, e2)                 // consume b+2
        LOAD8(e2, jb + (b + 5) * 8)
      }
      int m = nb - b;  // 3, 4, or 5
      GATHER8(g2, e2)
      FMA8(g0, e0)
      if (m == 3) {
        FMA8(g1, e1)
        FMA8(g2, e2)
      } else if (m == 4) {
        LOAD8(e0, jb + (b + 3) * 8)
        GATHER8(g0, e0)
        FMA8(g1, e1)
        FMA8(g2, e2)
        FMA8(g0, e0)
      } else {
        LOAD8(e0, jb + (b + 3) * 8)
        GATHER8(g0, e0)
        FMA8(g1, e1)
        LOAD8(e1, jb + (b + 4) * 8)
        GATHER8(g1, e1)
        FMA8(g2, e2)
        FMA8(g0, e0)
        FMA8(g1, e1)
      }
    } else if (nb == 2) {
      unsigned e0[8], e1[8], g0[8], g1[8];
      LOAD8(e0, jb)
      GATHER8(g0, e0)
      LOAD8(e1, jb + 8)
      GATHER8(g1, e1)
      FMA8(g0, e0)
      FMA8(g1, e1)
    } else if (nb == 1) {
      unsigned e0[8], g0[8];
      LOAD8(e0, jb)
      GATHER8(g0, e0)
      FMA8(g0, e0)
    }
    tile[wave * 4 + rr][2 * lane]     = a0 + a2;  // user u0 + 2*lane
    tile[wave * 4 + rr][2 * lane + 1] = a1 + a3;  // user u0 + 2*lane + 1
  }
#undef LOAD8
#undef GATHER8
#undef FMA8

  __syncthreads();
  // store [128u x 16r]; thread t -> (ul = t>>1, rseg = (t&1)*8), 2x f32x4 NT
  int ul = threadIdx.x >> 1;
  int rseg = (threadIdx.x & 1) * 8;
  float* op = &out[(size_t)(u0 + ul) * N_ITEMS + r0 + rseg];
  f32x4 o0, o1;
  o0.x = tile[rseg + 0][ul]; o0.y = tile[rseg + 1][ul];
  o0.z = tile[rseg + 2][ul]; o0.w = tile[rseg + 3][ul];
  o1.x = tile[rseg + 4][ul]; o1.y = tile[rseg + 5][ul];
  o1.z = tile[rseg + 6][ul]; o1.w = tile[rseg + 7][ul];
  __builtin_nontemporal_store(o0, reinterpret_cast<f32x4*>(op));
  __builtin_nontemporal_store(o1, reinterpret_cast<f32x4*>(op) + 1);
}

extern "C" void kernel_launch(void* const* d_in, const int* in_sizes, int n_in,
                              void* d_out, int out_size, void* d_ws, size_t ws_size,
                              hipStream_t stream) {
  const float* X      = (const float*)d_in[0];
  const float* S_vals = (const float*)d_in[1];
  const int*   S_rows = (const int*)d_in[2];
  const int*   S_cols = (const int*)d_in[3];
  float* out = (float*)d_out;

  char* ws = (char*)d_ws;
  unsigned short* XT = (unsigned short*)(ws + OFF_XT);
  unsigned* csr_pk   = (unsigned*)(ws + OFF_CSRPK);
  int* cnt           = (int*)(ws + OFF_CNT);

  hipMemsetAsync(cnt, 0, N_ITEMS * sizeof(int), stream);
  hipMemsetAsync(csr_pk, 0, (size_t)N_ITEMS * CAP * sizeof(unsigned), stream);
  prep_kernel<<<NT_BLOCKS + NS_BLOCKS, 256, 0, stream>>>(
      X, S_vals, S_rows, S_cols, XT, cnt, csr_pk);
  spmm_kernel<<<1250 * 16, 256, 0, stream>>>(cnt, csr_pk, XT, out);
}

// Round 14
// 1088.459 us; speedup vs baseline: 1.0031x; 1.0031x over previous
//
#include <hip/hip_runtime.h>

#define N_ITEMS 20000
#define N_USERS 2048
#define NNZ     4000000
#define LDP     2112   // padded XT leading dim (breaks L2/L3 set aliasing)
#define HALF_ITEMS 10000
#define CAP_H   192    // per-(row,half) bucket; Poisson(100), P(>192) ~ 1e-16

typedef float    f32x4 __attribute__((ext_vector_type(4)));
typedef unsigned u32x4 __attribute__((ext_vector_type(4)));

// ---------------- ws layout (bytes) ----------------
#define OFF_XT     ((size_t)0)                    // bf16 [20000][2112] = 84,480,000
#define OFF_CSRPK  ((size_t)84480000)             // u32 [40000][192] (col_local<<16|bf16val) = 30,720,000
#define OFF_CNT    (OFF_CSRPK + 30720000)         // int [40000]

static __device__ __forceinline__ unsigned short f2bf(float f) {
  unsigned u = __float_as_uint(f);
  unsigned r = (u + 0x7fffu + ((u >> 16) & 1u)) >> 16;
  return (unsigned short)r;
}

#define NT_BLOCKS (313 * 32)                 // transpose tiles
#define NS_BLOCKS ((NNZ / 4 + 255) / 256)    // scatter blocks (4 nnz/thread)

// Fused: transpose X -> XT (bf16, padded) + COO -> (row, col-half) buckets.
// entry = (col_local << 16) | bf16(val), col_local < 10000.
__global__ __launch_bounds__(256) void prep_kernel(
    const float* __restrict__ X, const float* __restrict__ vals,
    const int* __restrict__ rows, const int* __restrict__ cols,
    unsigned short* __restrict__ XT, int* __restrict__ cnt,
    unsigned* __restrict__ csr_pk) {
  int b = blockIdx.x;
  if (b < NT_BLOCKS) {
    __shared__ float tile[64][65];
    int k0 = (b % 313) * 64;
    int u0 = (b / 313) * 64;
    int lane = threadIdx.x & 63;
    int dq = threadIdx.x >> 6;
    #pragma unroll
    for (int m = 0; m < 16; ++m) {
      int u = u0 + dq + 4 * m;
      int k = k0 + lane;
      float v = 0.f;
      if (k < N_ITEMS) v = X[(size_t)u * N_ITEMS + k];
      tile[lane][dq + 4 * m] = v;
    }
    __syncthreads();
    #pragma unroll
    for (int m = 0; m < 16; ++m) {
      int k = k0 + dq + 4 * m;
      if (k < N_ITEMS)
        XT[(size_t)k * LDP + u0 + lane] = f2bf(tile[dq + 4 * m][lane]);
    }
  } else {
    int i = ((b - NT_BLOCKS) * 256 + threadIdx.x) * 4;
    if (i < NNZ) {  // NNZ % 4 == 0: quads always complete
      int4   r4 = *reinterpret_cast<const int4*>(rows + i);
      int4   c4 = *reinterpret_cast<const int4*>(cols + i);
      float4 v4 = *reinterpret_cast<const float4*>(vals + i);
      #pragma unroll
      for (int k = 0; k < 4; ++k) {
        int   r = (k == 0) ? r4.x : (k == 1) ? r4.y : (k == 2) ? r4.z : r4.w;
        int   c = (k == 0) ? c4.x : (k == 1) ? c4.y : (k == 2) ? c4.z : c4.w;
        float v = (k == 0) ? v4.x : (k == 1) ? v4.y : (k == 2) ? v4.z : v4.w;
        int h = (c >= HALF_ITEMS) ? 1 : 0;
        int bin = 2 * r + h;
        int pos = atomicAdd(&cnt[bin], 1);
        if (pos >= CAP_H) pos = CAP_H - 1;  // astronomically unlikely
        csr_pk[bin * CAP_H + pos] =
            ((unsigned)(c - h * HALF_ITEMS) << 16) | (unsigned)f2bf(v);
      }
    }
  }
}

// Phase-locked SpMM: ONE (uc, h) phase per dispatch; stream order between the
// 4 dispatches is the global barrier (cooperative API not needed).
// Within a dispatch, every WG on XCD x gathers ONLY from slice
// (uchunk 2x+uc, half h) = 128u x 10000 x 2B = 2.56 MB < 4 MB L2 -> pinned
// working set for the whole dispatch; no drift possible.
// WG: 256 thr = 4 waves; 8 rows x 128 users; grid 2500 rb x 8 xcd = 20000.
// h0: partial tile -> out via NT stores (bypass L2). h1: NT-load partials,
// accumulate, final NT store. No atomics; csr entries NT-loaded.
__global__ __launch_bounds__(256) void spmm_kernel(
    const int* __restrict__ cnt, const unsigned* __restrict__ csr_pk,
    const unsigned short* __restrict__ xt, float* __restrict__ out,
    int uc, int h) {
  __shared__ float tile[8][132];
  int wg = blockIdx.x;
  int xcd = wg & 7;
  int rb = wg >> 3;              // [0, 2500)
  int u0 = (xcd * 2 + uc) * 128;
  int r0 = rb * 8;
  int lane = threadIdx.x & 63;
  int wave = __builtin_amdgcn_readfirstlane((int)(threadIdx.x >> 6));
  unsigned lane4 = 4 * (unsigned)lane;
  const char* xtb = (const char*)(xt + (size_t)h * HALF_ITEMS * LDP + u0);
  int ul = threadIdx.x >> 1;          // user-local [0,128)
  int rhalf = (threadIdx.x & 1) * 4;  // row sub-block {0,4}
  float* op = out + (size_t)(u0 + ul) * N_ITEMS + r0 + rhalf;

#define LOAD8(E, BASE)                                                       \
  { u32x4 q0 = __builtin_nontemporal_load(                                   \
        reinterpret_cast<const u32x4*>(csr_pk + (BASE)));                    \
    u32x4 q1 = __builtin_nontemporal_load(                                   \
        reinterpret_cast<const u32x4*>(csr_pk + (BASE) + 4));                \
    E[0] = q0.x; E[1] = q0.y; E[2] = q0.z; E[3] = q0.w;                      \
    E[4] = q1.x; E[5] = q1.y; E[6] = q1.z; E[7] = q1.w; }
#define GATHER8(G, E)                                                        \
  { _Pragma("unroll")                                                        \
    for (int k = 0; k < 8; ++k)                                              \
      G[k] = *reinterpret_cast<const unsigned*>(                             \
          xtb + ((E[k] >> 16) * (unsigned)(LDP * 2) + lane4)); }
#define FMA8(G, E)                                                           \
  { _Pragma("unroll")                                                        \
    for (int k = 0; k < 8; ++k) {                                            \
      float v  = __uint_as_float(E[k] << 16);     /* exact bf16 */           \
      float xl = __uint_as_float(G[k] << 16);                                \
      float xh = __uint_as_float(G[k]);           /* lo bits = noise */      \
      if (k & 1) { a2 = fmaf(v, xl, a2); a3 = fmaf(v, xh, a3); }             \
      else       { a0 = fmaf(v, xl, a0); a1 = fmaf(v, xh, a1); }             \
    } }

  if (h) {  // stage h0 partials: coalesced NT loads -> LDS in acc layout
    f32x4 i0 = __builtin_nontemporal_load(reinterpret_cast<const f32x4*>(op));
    tile[rhalf + 0][ul] = i0.x; tile[rhalf + 1][ul] = i0.y;
    tile[rhalf + 2][ul] = i0.z; tile[rhalf + 3][ul] = i0.w;
    __syncthreads();
  }

  #pragma unroll 1
  for (int rr = 0; rr < 2; ++rr) {
    int r = r0 + wave * 2 + rr;
    int bin = 2 * r + h;
    int jb = bin * CAP_H;
    int cr = __builtin_amdgcn_readfirstlane(cnt[bin]);
    if (cr > CAP_H) cr = CAP_H;
    int nb = (cr + 7) >> 3;  // zero-padded buckets: all batches full
    float a0 = 0.f, a1 = 0.f, a2 = 0.f, a3 = 0.f;
    if (h) {  // own row's staged partials (written only at iteration end)
      a0 = tile[wave * 2 + rr][2 * lane];
      a1 = tile[wave * 2 + rr][2 * lane + 1];
    }
    if (nb >= 2) {
      unsigned e0[8], e1[8], g0[8], g1[8];
      LOAD8(e0, jb)
      GATHER8(g0, e0)
      LOAD8(e1, jb + 8)
      int b = 0;
      for (; b + 3 < nb; b += 2) {
        GATHER8(g1, e1)              // issue gathers b+1
        FMA8(g0, e0)                 // compute b
        LOAD8(e0, jb + (b + 2) * 8)
        GATHER8(g0, e0)              // issue gathers b+2
        FMA8(g1, e1)                 // compute b+1
        LOAD8(e1, jb + (b + 3) * 8)
      }
      GATHER8(g1, e1)
      FMA8(g0, e0)
      if (nb - b == 3) {
        LOAD8(e0, jb + (b + 2) * 8)
        GATHER8(g0, e0)
        FMA8(g1, e1)
        FMA8(g0, e0)
      } else {
        FMA8(g1, e1)
      }
    } else if (nb == 1) {
      unsigned e0[8], g0[8];
      LOAD8(e0, jb)
      GATHER8(g0, e0)
      FMA8(g0, e0)
    }
    tile[wave * 2 + rr][2 * lane]     = a0 + a2;
    tile[wave * 2 + rr][2 * lane + 1] = a1 + a3;
  }
#undef LOAD8
#undef GATHER8
#undef FMA8

  __syncthreads();
  f32x4 o;
  o.x = tile[rhalf + 0][ul]; o.y = tile[rhalf + 1][ul];
  o.z = tile[rhalf + 2][ul]; o.w = tile[rhalf + 3][ul];
  __builtin_nontemporal_store(o, reinterpret_cast<f32x4*>(op));
}

extern "C" void kernel_launch(void* const* d_in, const int* in_sizes, int n_in,
                              void* d_out, int out_size, void* d_ws, size_t ws_size,
                              hipStream_t stream) {
  const float* X      = (const float*)d_in[0];
  const float* S_vals = (const float*)d_in[1];
  const int*   S_rows = (const int*)d_in[2];
  const int*   S_cols = (const int*)d_in[3];
  float* out = (float*)d_out;

  char* ws = (char*)d_ws;
  unsigned short* XT = (unsigned short*)(ws + OFF_XT);
  unsigned* csr_pk   = (unsigned*)(ws + OFF_CSRPK);
  int* cnt           = (int*)(ws + OFF_CNT);

  hipMemsetAsync(cnt, 0, 2 * N_ITEMS * sizeof(int), stream);
  hipMemsetAsync(csr_pk, 0, (size_t)2 * N_ITEMS * CAP_H * sizeof(unsigned), stream);
  prep_kernel<<<NT_BLOCKS + NS_BLOCKS, 256, 0, stream>>>(
      X, S_vals, S_rows, S_cols, XT, cnt, csr_pk);
  // 4 phase dispatches; same-stream serialization = global barrier between
  // phases. Order: (uc0,h0) -> (uc0,h1) -> (uc1,h0) -> (uc1,h1).
  for (int p = 0; p < 4; ++p)
    spmm_kernel<<<2500 * 8, 256, 0, stream>>>(cnt, csr_pk, XT, out,
                                              p >> 1, p & 1);
}